// Round 14
// baseline (203.410 us; speedup 1.0000x reference)
//
#include <hip/hip_runtime.h>
#include <hip/hip_bf16.h>

#define HW 9216          // 96*96
#define NPC 18432        // per-channel element count for BN
#define NELEM 1179648    // 2*64*96*96
#define PSTR 584         // prL pos stride (bf16): %8==0 (16B align), 292dw = +4 banks/pos
#define XSTR 72          // patch x stride (bf16): %8==0, 36dw = +4 banks/pos
#define PATCH_B 7776     // 3*18*72*2 bytes
#define PRL_O 18688      // 16*584*2 bytes (per o)

typedef __attribute__((ext_vector_type(2))) float f32x2;
typedef __attribute__((ext_vector_type(4))) float f32x4v;
typedef __attribute__((ext_vector_type(8))) short short8v;   // 8 bf16 (4 VGPRs)

__device__ __forceinline__ f32x2 fma2(f32x2 a, f32x2 b, f32x2 c) {
#if __has_builtin(__builtin_elementwise_fma)
    return __builtin_elementwise_fma(a, b, c);
#else
    return f32x2{fmaf(a.x, b.x, c.x), fmaf(a.y, b.y, c.y)};
#endif
}
__device__ __forceinline__ float dot8v(f32x2 a0, f32x2 a1, f32x2 a2, f32x2 a3,
                                       f32x2 b0, f32x2 b1, f32x2 b2, f32x2 b3) {
    f32x2 acc = a0 * b0;
    acc = fma2(a1, b1, acc);
    acc = fma2(a2, b2, acc);
    acc = fma2(a3, b3, acc);
    return acc.x + acc.y;
}

template <int CTRL>
__device__ __forceinline__ float dpp_add(float x) {
    int y = __builtin_amdgcn_update_dpp(0, __float_as_int(x), CTRL, 0xF, 0xF, true);
    return x + __int_as_float(y);
}
template <int CTRL>
__device__ __forceinline__ f32x2 dpp_add2(f32x2 x) {   // packed pair: 2 movs + 1 pk add
    int ya = __builtin_amdgcn_update_dpp(0, __float_as_int(x.x), CTRL, 0xF, 0xF, true);
    int yb = __builtin_amdgcn_update_dpp(0, __float_as_int(x.y), CTRL, 0xF, 0xF, true);
    return x + f32x2{__int_as_float(ya), __int_as_float(yb)};
}
__device__ __forceinline__ float red_lo(float x) {   // sum over lane xor 1,2,4
    x = dpp_add<0xB1>(x);    // quad_perm [1,0,3,2]
    x = dpp_add<0x4E>(x);    // quad_perm [2,3,0,1]
    x = dpp_add<0x141>(x);   // row_half_mirror
    return x;
}
__device__ __forceinline__ f32x2 red_lo2(f32x2 x) {
    x = dpp_add2<0xB1>(x);
    x = dpp_add2<0x4E>(x);
    x = dpp_add2<0x141>(x);
    return x;
}

__device__ __forceinline__ int detect_is32(const unsigned short* __restrict__ w1u) {
    int lane = threadIdx.x & 63;
    int bad = 0;
    #pragma unroll
    for (int i = 0; i < 16; ++i) {
        unsigned short u = (unsigned short)(w1u[lane + i * 64] & 0x7FFF);
        bad |= (u >= 0x42C8);   // bf16 |v| >= 100 or NaN/Inf
    }
    return (__ballot(bad) != 0ULL) ? 1 : 0;
}

__device__ __forceinline__ float load_in(const void* p, int idx, int is32) {
    return is32 ? ((const float*)p)[idx]
                : __bfloat162float(((const __hip_bfloat16*)p)[idx]);
}

__device__ __forceinline__ float lo16(unsigned v) { return __int_as_float((int)(v << 16)); }
__device__ __forceinline__ float hi16(unsigned v) { return __int_as_float((int)(v & 0xFFFF0000u)); }
__device__ __forceinline__ unsigned pk2bf(float a, float b) {
    __hip_bfloat162 h = __float22bfloat162_rn(float2{a, b});
    return *(unsigned*)&h;
}

// ---------------------------------------------------------------------------
// prep: 0..143 MFMA B-fragment tables (both layers); 144 zero BN-stat accum.
// (x-transpose removed: caps layer-1 now stages straight from NCHW x.)
// ---------------------------------------------------------------------------
__launch_bounds__(256)
__global__ void prep_kernel(const void* __restrict__ w1, const void* __restrict__ w2,
                            __hip_bfloat16* __restrict__ Bfr1,
                            __hip_bfloat16* __restrict__ Bfr2,
                            float* __restrict__ statz) {
    const int bid = blockIdx.x;
    if (bid < 144) {
        const int is32 = detect_is32((const unsigned short*)w1);
        int t = bid * 256 + threadIdx.x;   // 0..36863
        int layer = t / 18432;
        int r = t - layer * 18432;
        int lane = r & 63;
        int fi = r >> 6;                 // 0..287 = ((o*9+k)*2+g)*2+h
        int h = fi & 1, g = (fi >> 1) & 1;
        int kq = fi >> 2;
        int k = kq % 9, o = kq / 9;
        int dy = k / 3, dx = k % 3;
        int quad = lane >> 4, colhi = (lane >> 3) & 1, m = lane & 7;
        int act = (quad == 2 * h + colhi);
        int i = g * 4 + 2 * h + colhi;
        const void* w = layer ? w2 : w1;
        __hip_bfloat16* dst = layer ? Bfr2 : Bfr1;
        #pragma unroll
        for (int j = 0; j < 8; ++j) {
            float v = act ? load_in(w, ((((o * 8 + i) * 3 + dy) * 3 + dx) * 8 + j) * 8 + m, is32)
                          : 0.f;
            dst[(fi * 64 + lane) * 8 + j] = __float2bfloat16(v);
        }
    } else {
        for (int e = threadIdx.x; e < 2048; e += 256) statz[e] = 0.f;
    }
}

// ---------------------------------------------------------------------------
// Fused capsule conv (MFMA) + routing + BN-stat partials.
// Block = 256 threads = 4 waves; tile = 16 x-positions x TWO o.
// Wave w = (o2 = w>>1, g = w&1). Patch staged ONCE for both o's.
//   layer1: direct from NCHW x (18-run coalesced scalar loads, dtype-flexible)
//   layer2: from yt1 bf16 [pos][c] (uint2) + inline BN1
// Phase 1: 9 taps x 2 halves one-shot MFMA -> plain b16 prL stores (R11 form;
//   the R12 DPP-pack variant serialized MFMA->DPP and regressed 30%).
// Phase 2: 32 routing units = 256 threads; m in-lane, DPP reductions.
// ---------------------------------------------------------------------------
__launch_bounds__(256, 3)
__global__ void caps_kernel(const __hip_bfloat16* __restrict__ in,  // [b][y][x][64] bf16 (layer2)
                            const void* __restrict__ xraw,          // NCHW x (layer1)
                            const float* __restrict__ statPrev,     // BN1 raw stats (layer2)
                            const void* __restrict__ gamma, const void* __restrict__ beta,
                            const void* __restrict__ wdt,           // w1, dtype probe
                            const __hip_bfloat16* __restrict__ Bfr,
                            __hip_bfloat16* __restrict__ yout,      // [b][y][x][64] bf16
                            float* __restrict__ statL,              // [8 copies][128]
                            int layer1) {
    __shared__ __align__(16) unsigned char smem[PATCH_B + 2 * PRL_O];
    __hip_bfloat16* patchH = (__hip_bfloat16*)smem;             // [q=row*18+xo][c] stride XSTR
    __hip_bfloat16* prH    = (__hip_bfloat16*)(smem + PATCH_B); // [o2]*9344 + [pos]*PSTR + (i*9+k)*8+m
    float* omF = (float*)smem;                // 1 KB, aliases patch (dead in epilogue)
    float* scL = (float*)(smem + PATCH_B);    // 256 B, aliases prL head (staging only)
    float* shL = scL + 64;

    const int gx    = blockIdx.x;    // 0..23
    const int opair = gx & 3;
    const int x0    = (gx >> 2) * 16;
    const int y  = blockIdx.y;
    const int b  = blockIdx.z;
    const int tid = threadIdx.x;

    if (layer1) {
        // ---- stage patch direct from NCHW x: rows y-1..y+1, cols x0-1..x0+16 ----
        const int is32 = detect_is32((const unsigned short*)wdt);
        for (int e = tid; e < 3456; e += 256) {
            int xo = e % 18;
            int q  = e / 18;             // 0..191
            int row = q % 3, c = q / 3;
            int yy = y + row - 1, xx = x0 + xo - 1;
            float v = 0.f;
            if (yy >= 0 && yy < 96 && xx >= 0 && xx < 96)
                v = load_in(xraw, ((b * 64 + c) * 96 + yy) * 96 + xx, is32);
            patchH[(row * 18 + xo) * XSTR + c] = __float2bfloat16(v);
        }
    } else {
        // ---- inline BN1 params ----
        if (tid < 64) {
            const int is32 = detect_is32((const unsigned short*)wdt);
            int c = tid;
            float s = 0.f, ss = 0.f;
            #pragma unroll
            for (int cp = 0; cp < 8; ++cp) {
                s  += statPrev[cp * 128 + c];
                ss += statPrev[cp * 128 + 64 + c];
            }
            float mean = s * (1.f / (float)NPC);
            float var  = fmaxf(ss * (1.f / (float)NPC) - mean * mean, 0.f);
            float inv  = rsqrtf(var + 1e-5f);
            float g = load_in(gamma, c, is32) * inv;
            scL[c] = g;
            shL[c] = load_in(beta, c, is32) - mean * g;
        }
        __syncthreads();
        // ---- stage patch from yt1 bf16 [pos][c] ----
        for (int e = tid; e < 864; e += 256) {
            int c4 = e & 15;             // 4-channel group
            int q  = e >> 4;             // 0..53 = row*18 + xo
            int xo = q % 18, row = q / 18;
            int yy = y + row - 1, xx = x0 + xo - 1;
            uint2 v = {0u, 0u};
            if (yy >= 0 && yy < 96 && xx >= 0 && xx < 96) {
                v = *(const uint2*)&in[((b * 96 + yy) * 96 + xx) * 64 + c4 * 4];
                int c = c4 * 4;
                float f0 = lo16(v.x) * scL[c]     + shL[c];
                float f1 = hi16(v.x) * scL[c + 1] + shL[c + 1];
                float f2 = lo16(v.y) * scL[c + 2] + shL[c + 2];
                float f3 = hi16(v.y) * scL[c + 3] + shL[c + 3];
                v.x = pk2bf(f0, f1);
                v.y = pk2bf(f2, f3);
            }
            *(uint2*)&patchH[q * XSTR + c4 * 4] = v;
        }
    }
    __syncthreads();

    const int lane = tid & 63;
    const int wv   = tid >> 6;       // wave 0..3
    const int o2w  = wv >> 1;        // which o of the pair
    const int g    = wv & 1;         // i-group

    // ================= Phase 1: priors via MFMA =================
    {
        const int o     = opair * 2 + o2w;
        const int rowA  = lane & 15;         // pos (A row)
        const int quad  = lane >> 4;
        const int colhi = (lane >> 3) & 1;
        const int m     = lane & 7;
        __hip_bfloat16* prBase = prH + o2w * 9344;
        #pragma unroll
        for (int k = 0; k < 9; ++k) {
            const int dy = k / 3, dx = k % 3;
            short8v a = *(const short8v*)&patchH[(dy * 18 + dx + rowA) * XSTR + g * 32 + quad * 8];
            #pragma unroll
            for (int h = 0; h < 2; ++h) {
                short8v bf = *(const short8v*)&Bfr[((((o * 9 + k) * 2 + g) * 2 + h) * 64 + lane) * 8];
                f32x4v d = __builtin_amdgcn_mfma_f32_16x16x32_bf16(a, bf, (f32x4v){0.f, 0.f, 0.f, 0.f}, 0, 0, 0);
                const int iw = g * 4 + 2 * h + colhi;
                const int basei = (iw * 9 + k) * 8 + m;
                #pragma unroll
                for (int r = 0; r < 4; ++r)
                    prBase[(quad * 4 + r) * PSTR + basei] = __float2bfloat16(d[r]);
            }
        }
    }
    __syncthreads();

    // ============ Phase 2: routing (unit = (o2,pos), lane-group = unit) ======
    const int unit = tid >> 3;       // 0..31
    const int o2   = unit >> 4;
    const int pos  = unit & 15;
    const int i    = tid & 7;
    const __hip_bfloat16* pb = &prH[o2 * 9344 + pos * PSTR + i * 72];

    uint4 u[9];
    #pragma unroll
    for (int k = 0; k < 9; ++k) u[k] = *(const uint4*)(pb + k * 8);

    f32x2 fr[36];
    float n1[9];
    #pragma unroll
    for (int k = 0; k < 9; ++k) {
        fr[4 * k + 0] = f32x2{lo16(u[k].x), hi16(u[k].x)};
        fr[4 * k + 1] = f32x2{lo16(u[k].y), hi16(u[k].y)};
        fr[4 * k + 2] = f32x2{lo16(u[k].z), hi16(u[k].z)};
        fr[4 * k + 3] = f32x2{lo16(u[k].w), hi16(u[k].w)};
    }

    // om init = mean over all 72 j: sum over k in-lane, then DPP-sum over i.
    f32x2 om2[4];
    {
        f32x2 s2[4] = {f32x2{0.f, 0.f}, f32x2{0.f, 0.f}, f32x2{0.f, 0.f}, f32x2{0.f, 0.f}};
        #pragma unroll
        for (int k = 0; k < 9; ++k) {
            s2[0] += fr[4 * k + 0];
            s2[1] += fr[4 * k + 1];
            s2[2] += fr[4 * k + 2];
            s2[3] += fr[4 * k + 3];
        }
        #pragma unroll
        for (int q = 0; q < 4; ++q) {
            f32x2 t = red_lo2(s2[q]);
            om2[q] = t * f32x2{1.f / 72.f, 1.f / 72.f};
        }
    }
    float n2 = dot8v(om2[0], om2[1], om2[2], om2[3], om2[0], om2[1], om2[2], om2[3]);

    #pragma unroll
    for (int it = 0; it < 3; ++it) {
        float se = 0.f;
        f32x2 acc2[4] = {f32x2{0.f, 0.f}, f32x2{0.f, 0.f}, f32x2{0.f, 0.f}, f32x2{0.f, 0.f}};
        #pragma unroll
        for (int k = 0; k < 9; ++k) {
            if (it == 0)
                n1[k] = dot8v(fr[4 * k], fr[4 * k + 1], fr[4 * k + 2], fr[4 * k + 3],
                              fr[4 * k], fr[4 * k + 1], fr[4 * k + 2], fr[4 * k + 3]);
            float d = dot8v(fr[4 * k], fr[4 * k + 1], fr[4 * k + 2], fr[4 * k + 3],
                            om2[0], om2[1], om2[2], om2[3]);
            float denom = fmaxf(n1[k] + n2 - d, 1e-8f);
            float e = __expf(d * __builtin_amdgcn_rcpf(denom));
            se += e;
            f32x2 ev{e, e};
            acc2[0] = fma2(ev, fr[4 * k + 0], acc2[0]);
            acc2[1] = fma2(ev, fr[4 * k + 1], acc2[1]);
            acc2[2] = fma2(ev, fr[4 * k + 2], acc2[2]);
            acc2[3] = fma2(ev, fr[4 * k + 3], acc2[3]);
        }
        se = red_lo(se);
        #pragma unroll
        for (int q = 0; q < 4; ++q) acc2[q] = red_lo2(acc2[q]);
        float inv = __builtin_amdgcn_rcpf(se);
        f32x2 iv{inv, inv};
        #pragma unroll
        for (int q = 0; q < 4; ++q) om2[q] = acc2[q] * iv;
        n2 = dot8v(om2[0], om2[1], om2[2], om2[3], om2[0], om2[1], om2[2], om2[3]);
    }

    if (i == 0) {
        const int o = opair * 2 + o2;
        uint4 pk;
        pk.x = pk2bf(om2[0].x, om2[0].y);
        pk.y = pk2bf(om2[1].x, om2[1].y);
        pk.z = pk2bf(om2[2].x, om2[2].y);
        pk.w = pk2bf(om2[3].x, om2[3].y);
        *(uint4*)&yout[((b * 96 + y) * 96 + x0 + pos) * 64 + o * 8] = pk;
        // park f32 finals for BN stats (patch region, dead)
        float4 o0 = {om2[0].x, om2[0].y, om2[1].x, om2[1].y};
        float4 o1 = {om2[2].x, om2[2].y, om2[3].x, om2[3].y};
        *(float4*)&omF[unit * 8] = o0;
        *(float4*)&omF[unit * 8 + 4] = o1;
    }
    __syncthreads();

    // ---- BN stat partials: this block's 16 channels, sum over 16 positions ----
    if (tid < 32) {
        int c16 = tid & 15, sel = tid >> 4;
        int oo2 = c16 >> 3, m = c16 & 7;
        float v = 0.f;
        #pragma unroll
        for (int pp = 0; pp < 16; ++pp) {
            float t = omF[(oo2 * 16 + pp) * 8 + m];
            v += sel ? t * t : t;
        }
        int cp = (blockIdx.x + blockIdx.y * 3 + blockIdx.z) & 7;
        atomicAdd(&statL[cp * 128 + sel * 64 + (opair * 2 + oo2) * 8 + m], v);
    }
}

// ---------------------------------------------------------------------------
// Final: out[b][c][y][x] = x + bn2(y2); bn2 params computed inline per block.
// ---------------------------------------------------------------------------
__launch_bounds__(256)
__global__ void final_kernel(const void* __restrict__ xin,
                             const __hip_bfloat16* __restrict__ yt2,
                             const float* __restrict__ statL,
                             const void* __restrict__ gamma, const void* __restrict__ beta,
                             const void* __restrict__ w1,
                             void* __restrict__ outp) {
    __shared__ float tile[64 * 33];
    __shared__ float scL[64], shL[64];
    const int is32 = detect_is32((const unsigned short*)w1);
    if (threadIdx.x < 64) {
        int c = threadIdx.x;
        float s = 0.f, ss = 0.f;
        #pragma unroll
        for (int cp = 0; cp < 8; ++cp) {
            s  += statL[cp * 128 + c];
            ss += statL[cp * 128 + 64 + c];
        }
        float mean = s * (1.f / (float)NPC);
        float var  = fmaxf(ss * (1.f / (float)NPC) - mean * mean, 0.f);
        float inv  = rsqrtf(var + 1e-5f);
        float g = load_in(gamma, c, is32) * inv;
        scL[c] = g;
        shL[c] = load_in(beta, c, is32) - mean * g;
    }
    __syncthreads();

    int x0 = blockIdx.x * 32, y = blockIdx.y, b = blockIdx.z;
    for (int e = threadIdx.x; e < 1024; e += 256) {
        int c2 = e & 31, xl = e >> 5;
        unsigned v = *(const unsigned*)&yt2[((b * 96 + y) * 96 + x0 + xl) * 64 + c2 * 2];
        int c = c2 * 2;
        tile[c * 33 + xl]       = lo16(v) * scL[c]     + shL[c];
        tile[(c + 1) * 33 + xl] = hi16(v) * scL[c + 1] + shL[c + 1];
    }
    __syncthreads();
    for (int f = threadIdx.x; f < 2048; f += 256) {
        int xl = f & 31, c = f >> 5;
        int idx = ((b * 64 + c) * 96 + y) * 96 + x0 + xl;
        float v = load_in(xin, idx, is32) + tile[c * 33 + xl];
        if (is32) ((float*)outp)[idx] = v;
        else      ((__hip_bfloat16*)outp)[idx] = __float2bfloat16(v);
    }
}

// ---------------------------------------------------------------------------
extern "C" void kernel_launch(void* const* d_in, const int* in_sizes, int n_in,
                              void* d_out, int out_size, void* d_ws, size_t ws_size,
                              hipStream_t stream) {
    const void* x  = d_in[0];
    const void* w1 = d_in[1];
    const void* g1 = d_in[2];
    const void* b1 = d_in[3];
    const void* w2 = d_in[4];
    const void* g2 = d_in[5];
    const void* b2 = d_in[6];

    __hip_bfloat16* bufA = (__hip_bfloat16*)d_ws;   // yt2 (bf16)
    __hip_bfloat16* bufB = bufA + NELEM;            // yt1 (bf16)
    __hip_bfloat16* Bfr1 = bufB + NELEM;            // 147456 bf16
    __hip_bfloat16* Bfr2 = Bfr1 + 147456;           // 147456 bf16
    float* statz = (float*)(Bfr2 + 147456);         // 2048 f32
    float* statL1 = statz;
    float* statL2 = statz + 1024;

    prep_kernel<<<145, 256, 0, stream>>>(w1, w2, Bfr1, Bfr2, statz);

    dim3 cgrid(24, 96, 2);   // (xtile of 16 x 4 o-pairs), rows, batch
    caps_kernel<<<cgrid, 256, 0, stream>>>(bufA, x, nullptr, nullptr, nullptr, w1,
                                           Bfr1, bufB, statL1, 1);
    caps_kernel<<<cgrid, 256, 0, stream>>>(bufB, nullptr, statL1, g1, b1, w1,
                                           Bfr2, bufA, statL2, 0);
    final_kernel<<<dim3(3, 96, 2), 256, 0, stream>>>(x, bufA, statL2, g2, b2, w1, d_out);
}

// Round 15
// 181.164 us; speedup vs baseline: 1.1228x; 1.1228x over previous
//
#include <hip/hip_runtime.h>
#include <hip/hip_bf16.h>

#define HW 9216          // 96*96
#define NPC 18432        // per-channel element count for BN
#define NELEM 1179648    // 2*64*96*96
#define PSTR 584         // prL pos stride (bf16): %8==0 (16B align), 292dw = +4 banks/pos
#define XSTR 72          // patch x stride (bf16): %8==0, 36dw = +4 banks/pos
#define PATCH_B 7776     // 3*18*72*2 bytes
#define PRL_O 18688      // 16*584*2 bytes (per o)

typedef __attribute__((ext_vector_type(2))) float f32x2;
typedef __attribute__((ext_vector_type(4))) float f32x4v;
typedef __attribute__((ext_vector_type(8))) short short8v;   // 8 bf16 (4 VGPRs)

__device__ __forceinline__ f32x2 fma2(f32x2 a, f32x2 b, f32x2 c) {
#if __has_builtin(__builtin_elementwise_fma)
    return __builtin_elementwise_fma(a, b, c);
#else
    return f32x2{fmaf(a.x, b.x, c.x), fmaf(a.y, b.y, c.y)};
#endif
}
__device__ __forceinline__ float dot8v(f32x2 a0, f32x2 a1, f32x2 a2, f32x2 a3,
                                       f32x2 b0, f32x2 b1, f32x2 b2, f32x2 b3) {
    f32x2 acc = a0 * b0;
    acc = fma2(a1, b1, acc);
    acc = fma2(a2, b2, acc);
    acc = fma2(a3, b3, acc);
    return acc.x + acc.y;
}

template <int CTRL>
__device__ __forceinline__ float dpp_add(float x) {
    int y = __builtin_amdgcn_update_dpp(0, __float_as_int(x), CTRL, 0xF, 0xF, true);
    return x + __int_as_float(y);
}
template <int CTRL>
__device__ __forceinline__ f32x2 dpp_add2(f32x2 x) {   // packed pair: 2 movs + 1 pk add
    int ya = __builtin_amdgcn_update_dpp(0, __float_as_int(x.x), CTRL, 0xF, 0xF, true);
    int yb = __builtin_amdgcn_update_dpp(0, __float_as_int(x.y), CTRL, 0xF, 0xF, true);
    return x + f32x2{__int_as_float(ya), __int_as_float(yb)};
}
__device__ __forceinline__ float red_lo(float x) {   // sum over lane xor 1,2,4
    x = dpp_add<0xB1>(x);    // quad_perm [1,0,3,2]
    x = dpp_add<0x4E>(x);    // quad_perm [2,3,0,1]
    x = dpp_add<0x141>(x);   // row_half_mirror
    return x;
}
__device__ __forceinline__ f32x2 red_lo2(f32x2 x) {
    x = dpp_add2<0xB1>(x);
    x = dpp_add2<0x4E>(x);
    x = dpp_add2<0x141>(x);
    return x;
}

__device__ __forceinline__ int detect_is32(const unsigned short* __restrict__ w1u) {
    int lane = threadIdx.x & 63;
    int bad = 0;
    #pragma unroll
    for (int i = 0; i < 16; ++i) {
        unsigned short u = (unsigned short)(w1u[lane + i * 64] & 0x7FFF);
        bad |= (u >= 0x42C8);   // bf16 |v| >= 100 or NaN/Inf
    }
    return (__ballot(bad) != 0ULL) ? 1 : 0;
}

__device__ __forceinline__ float load_in(const void* p, int idx, int is32) {
    return is32 ? ((const float*)p)[idx]
                : __bfloat162float(((const __hip_bfloat16*)p)[idx]);
}

__device__ __forceinline__ float lo16(unsigned v) { return __int_as_float((int)(v << 16)); }
__device__ __forceinline__ float hi16(unsigned v) { return __int_as_float((int)(v & 0xFFFF0000u)); }
__device__ __forceinline__ unsigned pk2bf(float a, float b) {
    __hip_bfloat162 h = __float22bfloat162_rn(float2{a, b});
    return *(unsigned*)&h;
}

// ---------------------------------------------------------------------------
// prep: 0..575 x-transpose to bf16 [b][y][x][c]; 576..719 MFMA B-fragment
// tables; 720 zero BN-stat accumulators.
// ---------------------------------------------------------------------------
__launch_bounds__(256)
__global__ void prep_kernel(const void* __restrict__ x,
                            const void* __restrict__ w1, const void* __restrict__ w2,
                            __hip_bfloat16* __restrict__ xt,
                            __hip_bfloat16* __restrict__ Bfr1,
                            __hip_bfloat16* __restrict__ Bfr2,
                            float* __restrict__ statz) {
    __shared__ float tile[64 * 33];
    const int bid = blockIdx.x;
    if (bid < 576) {
        const int is32 = detect_is32((const unsigned short*)w1);
        int xb = bid % 3, y = (bid / 3) % 96, b = bid / 288;
        int x0 = xb * 32;
        for (int e = threadIdx.x; e < 2048; e += 256) {
            int xl = e & 31, c = e >> 5;
            tile[c * 33 + xl] = load_in(x, ((b * 64 + c) * 96 + y) * 96 + x0 + xl, is32);
        }
        __syncthreads();
        for (int f = threadIdx.x; f < 1024; f += 256) {
            int c2 = f & 31, xl = f >> 5;
            float a = tile[(2 * c2) * 33 + xl];
            float c = tile[(2 * c2 + 1) * 33 + xl];
            *(unsigned*)&xt[((b * 96 + y) * 96 + x0 + xl) * 64 + 2 * c2] = pk2bf(a, c);
        }
    } else if (bid < 720) {
        const int is32 = detect_is32((const unsigned short*)w1);
        int t = (bid - 576) * 256 + threadIdx.x;   // 0..36863
        int layer = t / 18432;
        int r = t - layer * 18432;
        int lane = r & 63;
        int fi = r >> 6;                 // 0..287 = ((o*9+k)*2+g)*2+h
        int h = fi & 1, g = (fi >> 1) & 1;
        int kq = fi >> 2;
        int k = kq % 9, o = kq / 9;
        int dy = k / 3, dx = k % 3;
        int quad = lane >> 4, colhi = (lane >> 3) & 1, m = lane & 7;
        int act = (quad == 2 * h + colhi);
        int i = g * 4 + 2 * h + colhi;
        const void* w = layer ? w2 : w1;
        __hip_bfloat16* dst = layer ? Bfr2 : Bfr1;
        #pragma unroll
        for (int j = 0; j < 8; ++j) {
            float v = act ? load_in(w, ((((o * 8 + i) * 3 + dy) * 3 + dx) * 8 + j) * 8 + m, is32)
                          : 0.f;
            dst[(fi * 64 + lane) * 8 + j] = __float2bfloat16(v);
        }
    } else {
        for (int e = threadIdx.x; e < 2048; e += 256) statz[e] = 0.f;
    }
}

// ---------------------------------------------------------------------------
// Fused capsule conv (MFMA) + routing + BN-stat partials.  (R13 structure)
// Block = 256 threads = 4 waves; tile = 16 x-positions x TWO o.
// Wave w = (o2 = w>>1, g = w&1). Patch staged ONCE for both o's (bf16 uint2).
// NEW (R15): the 18 Bfr B-fragments are prefetched into registers at kernel
// entry (before the staging barrier) so phase-1 MFMAs never wait on vmcnt.
// Phase 1: 9 taps x 2 halves one-shot MFMA -> plain b16 prL stores.
// Phase 2: 32 routing units = 256 threads; m in-lane, DPP reductions.
// ---------------------------------------------------------------------------
__launch_bounds__(256, 3)
__global__ void caps_kernel(const __hip_bfloat16* __restrict__ in,  // [b][y][x][64] bf16
                            const float* __restrict__ statPrev,     // BN1 raw stats (layer2)
                            const void* __restrict__ gamma, const void* __restrict__ beta,
                            const void* __restrict__ wdt,           // w1, dtype probe
                            const __hip_bfloat16* __restrict__ Bfr,
                            __hip_bfloat16* __restrict__ yout,      // [b][y][x][64] bf16
                            float* __restrict__ statL,              // [8 copies][128]
                            int layer1) {
    __shared__ __align__(16) unsigned char smem[PATCH_B + 2 * PRL_O];
    __hip_bfloat16* patchH = (__hip_bfloat16*)smem;             // [q=row*18+xo][c] stride XSTR
    __hip_bfloat16* prH    = (__hip_bfloat16*)(smem + PATCH_B); // [o2]*9344 + [pos]*PSTR + (i*9+k)*8+m
    float* omF = (float*)smem;                // 1 KB, aliases patch (dead in epilogue)
    float* scL = (float*)(smem + PATCH_B);    // 256 B, aliases prL head (staging only)
    float* shL = scL + 64;

    const int gx    = blockIdx.x;    // 0..23
    const int opair = gx & 3;
    const int x0    = (gx >> 2) * 16;
    const int y  = blockIdx.y;
    const int b  = blockIdx.z;
    const int tid = threadIdx.x;

    const int lane = tid & 63;
    const int wv   = tid >> 6;       // wave 0..3
    const int o2w  = wv >> 1;        // which o of the pair
    const int g    = wv & 1;         // i-group
    const int oW   = opair * 2 + o2w;

    // ---- prefetch B-fragments into registers (overlaps staging below) ----
    short8v bfr[18];
    #pragma unroll
    for (int k = 0; k < 9; ++k) {
        #pragma unroll
        for (int h = 0; h < 2; ++h)
            bfr[k * 2 + h] = *(const short8v*)&Bfr[((((oW * 9 + k) * 2 + g) * 2 + h) * 64 + lane) * 8];
    }

    // ---- inline BN1 params (layer 2 only) ----
    if (!layer1) {
        if (tid < 64) {
            const int is32 = detect_is32((const unsigned short*)wdt);
            int c = tid;
            float s = 0.f, ss = 0.f;
            #pragma unroll
            for (int cp = 0; cp < 8; ++cp) {
                s  += statPrev[cp * 128 + c];
                ss += statPrev[cp * 128 + 64 + c];
            }
            float mean = s * (1.f / (float)NPC);
            float var  = fmaxf(ss * (1.f / (float)NPC) - mean * mean, 0.f);
            float inv  = rsqrtf(var + 1e-5f);
            float gg = load_in(gamma, c, is32) * inv;
            scL[c] = gg;
            shL[c] = load_in(beta, c, is32) - mean * gg;
        }
        __syncthreads();
    }

    // ---- stage patch: rows y-1..y+1, cols x0-1..x0+16, 64 ch bf16 ----
    for (int e = tid; e < 864; e += 256) {
        int c4 = e & 15;             // 4-channel group
        int q  = e >> 4;             // 0..53 = row*18 + xo
        int xo = q % 18, row = q / 18;
        int yy = y + row - 1, xx = x0 + xo - 1;
        uint2 v = {0u, 0u};
        if (yy >= 0 && yy < 96 && xx >= 0 && xx < 96) {
            v = *(const uint2*)&in[((b * 96 + yy) * 96 + xx) * 64 + c4 * 4];
            if (!layer1) {
                int c = c4 * 4;
                float f0 = lo16(v.x) * scL[c]     + shL[c];
                float f1 = hi16(v.x) * scL[c + 1] + shL[c + 1];
                float f2 = lo16(v.y) * scL[c + 2] + shL[c + 2];
                float f3 = hi16(v.y) * scL[c + 3] + shL[c + 3];
                v.x = pk2bf(f0, f1);
                v.y = pk2bf(f2, f3);
            }
        }
        *(uint2*)&patchH[q * XSTR + c4 * 4] = v;
    }
    __syncthreads();

    // ================= Phase 1: priors via MFMA =================
    {
        const int rowA  = lane & 15;         // pos (A row)
        const int quad  = lane >> 4;
        const int colhi = (lane >> 3) & 1;
        const int m     = lane & 7;
        __hip_bfloat16* prBase = prH + o2w * 9344;
        #pragma unroll
        for (int k = 0; k < 9; ++k) {
            const int dy = k / 3, dx = k % 3;
            short8v a = *(const short8v*)&patchH[(dy * 18 + dx + rowA) * XSTR + g * 32 + quad * 8];
            #pragma unroll
            for (int h = 0; h < 2; ++h) {
                f32x4v d = __builtin_amdgcn_mfma_f32_16x16x32_bf16(a, bfr[k * 2 + h], (f32x4v){0.f, 0.f, 0.f, 0.f}, 0, 0, 0);
                const int iw = g * 4 + 2 * h + colhi;
                const int basei = (iw * 9 + k) * 8 + m;
                #pragma unroll
                for (int r = 0; r < 4; ++r)
                    prBase[(quad * 4 + r) * PSTR + basei] = __float2bfloat16(d[r]);
            }
        }
    }
    __syncthreads();

    // ============ Phase 2: routing (unit = (o2,pos), lane-group = unit) ======
    const int unit = tid >> 3;       // 0..31
    const int o2   = unit >> 4;
    const int pos  = unit & 15;
    const int i    = tid & 7;
    const __hip_bfloat16* pb = &prH[o2 * 9344 + pos * PSTR + i * 72];

    uint4 u[9];
    #pragma unroll
    for (int k = 0; k < 9; ++k) u[k] = *(const uint4*)(pb + k * 8);

    f32x2 fr[36];
    float n1[9];
    #pragma unroll
    for (int k = 0; k < 9; ++k) {
        fr[4 * k + 0] = f32x2{lo16(u[k].x), hi16(u[k].x)};
        fr[4 * k + 1] = f32x2{lo16(u[k].y), hi16(u[k].y)};
        fr[4 * k + 2] = f32x2{lo16(u[k].z), hi16(u[k].z)};
        fr[4 * k + 3] = f32x2{lo16(u[k].w), hi16(u[k].w)};
    }

    // om init = mean over all 72 j: sum over k in-lane, then DPP-sum over i.
    f32x2 om2[4];
    {
        f32x2 s2[4] = {f32x2{0.f, 0.f}, f32x2{0.f, 0.f}, f32x2{0.f, 0.f}, f32x2{0.f, 0.f}};
        #pragma unroll
        for (int k = 0; k < 9; ++k) {
            s2[0] += fr[4 * k + 0];
            s2[1] += fr[4 * k + 1];
            s2[2] += fr[4 * k + 2];
            s2[3] += fr[4 * k + 3];
        }
        #pragma unroll
        for (int q = 0; q < 4; ++q) {
            f32x2 t = red_lo2(s2[q]);
            om2[q] = t * f32x2{1.f / 72.f, 1.f / 72.f};
        }
    }
    float n2 = dot8v(om2[0], om2[1], om2[2], om2[3], om2[0], om2[1], om2[2], om2[3]);

    #pragma unroll
    for (int it = 0; it < 3; ++it) {
        float se = 0.f;
        f32x2 acc2[4] = {f32x2{0.f, 0.f}, f32x2{0.f, 0.f}, f32x2{0.f, 0.f}, f32x2{0.f, 0.f}};
        #pragma unroll
        for (int k = 0; k < 9; ++k) {
            if (it == 0)
                n1[k] = dot8v(fr[4 * k], fr[4 * k + 1], fr[4 * k + 2], fr[4 * k + 3],
                              fr[4 * k], fr[4 * k + 1], fr[4 * k + 2], fr[4 * k + 3]);
            float d = dot8v(fr[4 * k], fr[4 * k + 1], fr[4 * k + 2], fr[4 * k + 3],
                            om2[0], om2[1], om2[2], om2[3]);
            float denom = fmaxf(n1[k] + n2 - d, 1e-8f);
            float e = __expf(d * __builtin_amdgcn_rcpf(denom));
            se += e;
            f32x2 ev{e, e};
            acc2[0] = fma2(ev, fr[4 * k + 0], acc2[0]);
            acc2[1] = fma2(ev, fr[4 * k + 1], acc2[1]);
            acc2[2] = fma2(ev, fr[4 * k + 2], acc2[2]);
            acc2[3] = fma2(ev, fr[4 * k + 3], acc2[3]);
        }
        se = red_lo(se);
        #pragma unroll
        for (int q = 0; q < 4; ++q) acc2[q] = red_lo2(acc2[q]);
        float inv = __builtin_amdgcn_rcpf(se);
        f32x2 iv{inv, inv};
        #pragma unroll
        for (int q = 0; q < 4; ++q) om2[q] = acc2[q] * iv;
        n2 = dot8v(om2[0], om2[1], om2[2], om2[3], om2[0], om2[1], om2[2], om2[3]);
    }

    if (i == 0) {
        const int o = opair * 2 + o2;
        uint4 pk;
        pk.x = pk2bf(om2[0].x, om2[0].y);
        pk.y = pk2bf(om2[1].x, om2[1].y);
        pk.z = pk2bf(om2[2].x, om2[2].y);
        pk.w = pk2bf(om2[3].x, om2[3].y);
        *(uint4*)&yout[((b * 96 + y) * 96 + x0 + pos) * 64 + o * 8] = pk;
        // park f32 finals for BN stats (patch region, dead)
        float4 o0 = {om2[0].x, om2[0].y, om2[1].x, om2[1].y};
        float4 o1 = {om2[2].x, om2[2].y, om2[3].x, om2[3].y};
        *(float4*)&omF[unit * 8] = o0;
        *(float4*)&omF[unit * 8 + 4] = o1;
    }
    __syncthreads();

    // ---- BN stat partials: this block's 16 channels, sum over 16 positions ----
    if (tid < 32) {
        int c16 = tid & 15, sel = tid >> 4;
        int oo2 = c16 >> 3, m = c16 & 7;
        float v = 0.f;
        #pragma unroll
        for (int pp = 0; pp < 16; ++pp) {
            float t = omF[(oo2 * 16 + pp) * 8 + m];
            v += sel ? t * t : t;
        }
        int cp = (blockIdx.x + blockIdx.y * 3 + blockIdx.z) & 7;
        atomicAdd(&statL[cp * 128 + sel * 64 + (opair * 2 + oo2) * 8 + m], v);
    }
}

// ---------------------------------------------------------------------------
// Final: out[b][c][y][x] = x + bn2(y2); bn2 params computed inline per block.
// ---------------------------------------------------------------------------
__launch_bounds__(256)
__global__ void final_kernel(const void* __restrict__ xin,
                             const __hip_bfloat16* __restrict__ yt2,
                             const float* __restrict__ statL,
                             const void* __restrict__ gamma, const void* __restrict__ beta,
                             const void* __restrict__ w1,
                             void* __restrict__ outp) {
    __shared__ float tile[64 * 33];
    __shared__ float scL[64], shL[64];
    const int is32 = detect_is32((const unsigned short*)w1);
    if (threadIdx.x < 64) {
        int c = threadIdx.x;
        float s = 0.f, ss = 0.f;
        #pragma unroll
        for (int cp = 0; cp < 8; ++cp) {
            s  += statL[cp * 128 + c];
            ss += statL[cp * 128 + 64 + c];
        }
        float mean = s * (1.f / (float)NPC);
        float var  = fmaxf(ss * (1.f / (float)NPC) - mean * mean, 0.f);
        float inv  = rsqrtf(var + 1e-5f);
        float g = load_in(gamma, c, is32) * inv;
        scL[c] = g;
        shL[c] = load_in(beta, c, is32) - mean * g;
    }
    __syncthreads();

    int x0 = blockIdx.x * 32, y = blockIdx.y, b = blockIdx.z;
    for (int e = threadIdx.x; e < 1024; e += 256) {
        int c2 = e & 31, xl = e >> 5;
        unsigned v = *(const unsigned*)&yt2[((b * 96 + y) * 96 + x0 + xl) * 64 + c2 * 2];
        int c = c2 * 2;
        tile[c * 33 + xl]       = lo16(v) * scL[c]     + shL[c];
        tile[(c + 1) * 33 + xl] = hi16(v) * scL[c + 1] + shL[c + 1];
    }
    __syncthreads();
    for (int f = threadIdx.x; f < 2048; f += 256) {
        int xl = f & 31, c = f >> 5;
        int idx = ((b * 64 + c) * 96 + y) * 96 + x0 + xl;
        float v = load_in(xin, idx, is32) + tile[c * 33 + xl];
        if (is32) ((float*)outp)[idx] = v;
        else      ((__hip_bfloat16*)outp)[idx] = __float2bfloat16(v);
    }
}

// ---------------------------------------------------------------------------
extern "C" void kernel_launch(void* const* d_in, const int* in_sizes, int n_in,
                              void* d_out, int out_size, void* d_ws, size_t ws_size,
                              hipStream_t stream) {
    const void* x  = d_in[0];
    const void* w1 = d_in[1];
    const void* g1 = d_in[2];
    const void* b1 = d_in[3];
    const void* w2 = d_in[4];
    const void* g2 = d_in[5];
    const void* b2 = d_in[6];

    __hip_bfloat16* bufA = (__hip_bfloat16*)d_ws;   // xt / yt2 (bf16, aliased)
    __hip_bfloat16* bufB = bufA + NELEM;            // yt1 (bf16)
    __hip_bfloat16* Bfr1 = bufB + NELEM;            // 147456 bf16
    __hip_bfloat16* Bfr2 = Bfr1 + 147456;           // 147456 bf16
    float* statz = (float*)(Bfr2 + 147456);         // 2048 f32
    float* statL1 = statz;
    float* statL2 = statz + 1024;

    prep_kernel<<<721, 256, 0, stream>>>(x, w1, w2, bufA, Bfr1, Bfr2, statz);

    dim3 cgrid(24, 96, 2);   // (xtile of 16 x 4 o-pairs), rows, batch
    caps_kernel<<<cgrid, 256, 0, stream>>>(bufA, nullptr, nullptr, nullptr, w1,
                                           Bfr1, bufB, statL1, 1);
    caps_kernel<<<cgrid, 256, 0, stream>>>(bufB, statL1, g1, b1, w1,
                                           Bfr2, bufA, statL2, 0);
    final_kernel<<<dim3(3, 96, 2), 256, 0, stream>>>(x, bufA, statL2, g2, b2, w1, d_out);
}

// Round 16
// 178.072 us; speedup vs baseline: 1.1423x; 1.0174x over previous
//
#include <hip/hip_runtime.h>
#include <hip/hip_bf16.h>

#define HW 9216          // 96*96
#define NPC 18432        // per-channel element count for BN
#define NELEM 1179648    // 2*64*96*96
#define PSTR 584         // prL pos stride (bf16): %8==0 (16B align), 292dw = +4 banks/pos
#define XSTR 72          // patch x stride (bf16): %8==0, 36dw = +4 banks/pos
#define PATCH_B 7776     // 3*18*72*2 bytes
#define PRL_O 18688      // 16*584*2 bytes (per o)

typedef __attribute__((ext_vector_type(2))) float f32x2;
typedef __attribute__((ext_vector_type(4))) float f32x4v;
typedef __attribute__((ext_vector_type(8))) short short8v;   // 8 bf16 (4 VGPRs)

__device__ __forceinline__ f32x2 fma2(f32x2 a, f32x2 b, f32x2 c) {
#if __has_builtin(__builtin_elementwise_fma)
    return __builtin_elementwise_fma(a, b, c);
#else
    return f32x2{fmaf(a.x, b.x, c.x), fmaf(a.y, b.y, c.y)};
#endif
}
__device__ __forceinline__ float dot8v(f32x2 a0, f32x2 a1, f32x2 a2, f32x2 a3,
                                       f32x2 b0, f32x2 b1, f32x2 b2, f32x2 b3) {
    f32x2 acc = a0 * b0;
    acc = fma2(a1, b1, acc);
    acc = fma2(a2, b2, acc);
    acc = fma2(a3, b3, acc);
    return acc.x + acc.y;
}

template <int CTRL>
__device__ __forceinline__ float dpp_add(float x) {
    int y = __builtin_amdgcn_update_dpp(0, __float_as_int(x), CTRL, 0xF, 0xF, true);
    return x + __int_as_float(y);
}
template <int CTRL>
__device__ __forceinline__ f32x2 dpp_add2(f32x2 x) {   // packed pair: 2 movs + 1 pk add
    int ya = __builtin_amdgcn_update_dpp(0, __float_as_int(x.x), CTRL, 0xF, 0xF, true);
    int yb = __builtin_amdgcn_update_dpp(0, __float_as_int(x.y), CTRL, 0xF, 0xF, true);
    return x + f32x2{__int_as_float(ya), __int_as_float(yb)};
}
__device__ __forceinline__ float red_lo(float x) {   // sum over lane xor 1,2,4
    x = dpp_add<0xB1>(x);    // quad_perm [1,0,3,2]
    x = dpp_add<0x4E>(x);    // quad_perm [2,3,0,1]
    x = dpp_add<0x141>(x);   // row_half_mirror
    return x;
}
__device__ __forceinline__ f32x2 red_lo2(f32x2 x) {
    x = dpp_add2<0xB1>(x);
    x = dpp_add2<0x4E>(x);
    x = dpp_add2<0x141>(x);
    return x;
}

__device__ __forceinline__ int detect_is32(const unsigned short* __restrict__ w1u) {
    int lane = threadIdx.x & 63;
    int bad = 0;
    #pragma unroll
    for (int i = 0; i < 16; ++i) {
        unsigned short u = (unsigned short)(w1u[lane + i * 64] & 0x7FFF);
        bad |= (u >= 0x42C8);   // bf16 |v| >= 100 or NaN/Inf
    }
    return (__ballot(bad) != 0ULL) ? 1 : 0;
}

__device__ __forceinline__ float load_in(const void* p, int idx, int is32) {
    return is32 ? ((const float*)p)[idx]
                : __bfloat162float(((const __hip_bfloat16*)p)[idx]);
}

__device__ __forceinline__ float lo16(unsigned v) { return __int_as_float((int)(v << 16)); }
__device__ __forceinline__ float hi16(unsigned v) { return __int_as_float((int)(v & 0xFFFF0000u)); }
__device__ __forceinline__ unsigned pk2bf(float a, float b) {
    __hip_bfloat162 h = __float22bfloat162_rn(float2{a, b});
    return *(unsigned*)&h;
}

// ---------------------------------------------------------------------------
// prep: 0..575 x-transpose to bf16 [b][y][x][c]; 576..719 MFMA B-fragment
// tables; 720 zero BN-stat accumulators.
// ---------------------------------------------------------------------------
__launch_bounds__(256)
__global__ void prep_kernel(const void* __restrict__ x,
                            const void* __restrict__ w1, const void* __restrict__ w2,
                            __hip_bfloat16* __restrict__ xt,
                            __hip_bfloat16* __restrict__ Bfr1,
                            __hip_bfloat16* __restrict__ Bfr2,
                            float* __restrict__ statz) {
    __shared__ float tile[64 * 33];
    const int bid = blockIdx.x;
    if (bid < 576) {
        const int is32 = detect_is32((const unsigned short*)w1);
        int xb = bid % 3, y = (bid / 3) % 96, b = bid / 288;
        int x0 = xb * 32;
        for (int e = threadIdx.x; e < 2048; e += 256) {
            int xl = e & 31, c = e >> 5;
            tile[c * 33 + xl] = load_in(x, ((b * 64 + c) * 96 + y) * 96 + x0 + xl, is32);
        }
        __syncthreads();
        for (int f = threadIdx.x; f < 1024; f += 256) {
            int c2 = f & 31, xl = f >> 5;
            float a = tile[(2 * c2) * 33 + xl];
            float c = tile[(2 * c2 + 1) * 33 + xl];
            *(unsigned*)&xt[((b * 96 + y) * 96 + x0 + xl) * 64 + 2 * c2] = pk2bf(a, c);
        }
    } else if (bid < 720) {
        const int is32 = detect_is32((const unsigned short*)w1);
        int t = (bid - 576) * 256 + threadIdx.x;   // 0..36863
        int layer = t / 18432;
        int r = t - layer * 18432;
        int lane = r & 63;
        int fi = r >> 6;                 // 0..287 = ((o*9+k)*2+g)*2+h
        int h = fi & 1, g = (fi >> 1) & 1;
        int kq = fi >> 2;
        int k = kq % 9, o = kq / 9;
        int dy = k / 3, dx = k % 3;
        int quad = lane >> 4, colhi = (lane >> 3) & 1, m = lane & 7;
        int act = (quad == 2 * h + colhi);
        int i = g * 4 + 2 * h + colhi;
        const void* w = layer ? w2 : w1;
        __hip_bfloat16* dst = layer ? Bfr2 : Bfr1;
        #pragma unroll
        for (int j = 0; j < 8; ++j) {
            float v = act ? load_in(w, ((((o * 8 + i) * 3 + dy) * 3 + dx) * 8 + j) * 8 + m, is32)
                          : 0.f;
            dst[(fi * 64 + lane) * 8 + j] = __float2bfloat16(v);
        }
    } else {
        for (int e = threadIdx.x; e < 2048; e += 256) statz[e] = 0.f;
    }
}

// ---------------------------------------------------------------------------
// Fused capsule conv (MFMA) + routing + BN-stat partials.  (R13 structure)
// Block = 256 threads = 4 waves; tile = 16 x-positions x TWO o.
// Wave w = (o2 = w>>1, g = w&1). Patch staged ONCE for both o's (bf16 uint2).
// Phase 1 (R16): OPERAND-SWAPPED MFMA — D = Bfr(A-role) x patch(B-role), so
//   each lane's 4 acc regs are 4 consecutive m of one (pos,i') => one
//   ds_write_b64 per MFMA instead of 4 ds_write_b16 (same Bfr table, same
//   patch load address: A/B fragment lane maps are mirrored).
// Phase 2: 32 routing units = 256 threads; m in-lane, DPP reductions.
// ---------------------------------------------------------------------------
__launch_bounds__(256, 3)
__global__ void caps_kernel(const __hip_bfloat16* __restrict__ in,  // [b][y][x][64] bf16
                            const float* __restrict__ statPrev,     // BN1 raw stats (layer2)
                            const void* __restrict__ gamma, const void* __restrict__ beta,
                            const void* __restrict__ wdt,           // w1, dtype probe
                            const __hip_bfloat16* __restrict__ Bfr,
                            __hip_bfloat16* __restrict__ yout,      // [b][y][x][64] bf16
                            float* __restrict__ statL,              // [8 copies][128]
                            int layer1) {
    __shared__ __align__(16) unsigned char smem[PATCH_B + 2 * PRL_O];
    __hip_bfloat16* patchH = (__hip_bfloat16*)smem;             // [q=row*18+xo][c] stride XSTR
    __hip_bfloat16* prH    = (__hip_bfloat16*)(smem + PATCH_B); // [o2]*9344 + [pos]*PSTR + (i*9+k)*8+m
    float* omF = (float*)smem;                // 1 KB, aliases patch (dead in epilogue)
    float* scL = (float*)(smem + PATCH_B);    // 256 B, aliases prL head (staging only)
    float* shL = scL + 64;

    const int gx    = blockIdx.x;    // 0..23
    const int opair = gx & 3;
    const int x0    = (gx >> 2) * 16;
    const int y  = blockIdx.y;
    const int b  = blockIdx.z;
    const int tid = threadIdx.x;

    // ---- inline BN1 params (layer 2 only) ----
    if (!layer1) {
        if (tid < 64) {
            const int is32 = detect_is32((const unsigned short*)wdt);
            int c = tid;
            float s = 0.f, ss = 0.f;
            #pragma unroll
            for (int cp = 0; cp < 8; ++cp) {
                s  += statPrev[cp * 128 + c];
                ss += statPrev[cp * 128 + 64 + c];
            }
            float mean = s * (1.f / (float)NPC);
            float var  = fmaxf(ss * (1.f / (float)NPC) - mean * mean, 0.f);
            float inv  = rsqrtf(var + 1e-5f);
            float g = load_in(gamma, c, is32) * inv;
            scL[c] = g;
            shL[c] = load_in(beta, c, is32) - mean * g;
        }
        __syncthreads();
    }

    // ---- stage patch: rows y-1..y+1, cols x0-1..x0+16, 64 ch bf16 ----
    for (int e = tid; e < 864; e += 256) {
        int c4 = e & 15;             // 4-channel group
        int q  = e >> 4;             // 0..53 = row*18 + xo
        int xo = q % 18, row = q / 18;
        int yy = y + row - 1, xx = x0 + xo - 1;
        uint2 v = {0u, 0u};
        if (yy >= 0 && yy < 96 && xx >= 0 && xx < 96) {
            v = *(const uint2*)&in[((b * 96 + yy) * 96 + xx) * 64 + c4 * 4];
            if (!layer1) {
                int c = c4 * 4;
                float f0 = lo16(v.x) * scL[c]     + shL[c];
                float f1 = hi16(v.x) * scL[c + 1] + shL[c + 1];
                float f2 = lo16(v.y) * scL[c + 2] + shL[c + 2];
                float f3 = hi16(v.y) * scL[c + 3] + shL[c + 3];
                v.x = pk2bf(f0, f1);
                v.y = pk2bf(f2, f3);
            }
        }
        *(uint2*)&patchH[q * XSTR + c4 * 4] = v;
    }
    __syncthreads();

    const int lane = tid & 63;
    const int wv   = tid >> 6;       // wave 0..3
    const int o2w  = wv >> 1;        // which o of the pair
    const int g    = wv & 1;         // i-group

    // ================= Phase 1: priors via operand-swapped MFMA =============
    {
        const int o     = opair * 2 + o2w;
        const int pos16 = lane & 15;         // B col = position
        const int quad  = lane >> 4;
        const int mbase = (quad & 1) * 4;    // D rows quad*4+r => m = mbase+r
        const int ihl   = quad >> 1;         // i'-local (within the h pair)
        __hip_bfloat16* prBase = prH + o2w * 9344;
        #pragma unroll
        for (int k = 0; k < 9; ++k) {
            const int dy = k / 3, dx = k % 3;
            short8v a = *(const short8v*)&patchH[(dy * 18 + dx + pos16) * XSTR + g * 32 + quad * 8];
            #pragma unroll
            for (int h = 0; h < 2; ++h) {
                short8v bf = *(const short8v*)&Bfr[((((o * 9 + k) * 2 + g) * 2 + h) * 64 + lane) * 8];
                // A = weight fragment, B = patch fragment (mirrored lane maps)
                f32x4v d = __builtin_amdgcn_mfma_f32_16x16x32_bf16(bf, a, (f32x4v){0.f, 0.f, 0.f, 0.f}, 0, 0, 0);
                const int iw = g * 4 + 2 * h + ihl;
                uint2 pk;
                pk.x = pk2bf(d[0], d[1]);
                pk.y = pk2bf(d[2], d[3]);
                *(uint2*)&prBase[pos16 * PSTR + (iw * 9 + k) * 8 + mbase] = pk;
            }
        }
    }
    __syncthreads();

    // ============ Phase 2: routing (unit = (o2,pos), lane-group = unit) ======
    const int unit = tid >> 3;       // 0..31
    const int o2   = unit >> 4;
    const int pos  = unit & 15;
    const int i    = tid & 7;
    const __hip_bfloat16* pb = &prH[o2 * 9344 + pos * PSTR + i * 72];

    uint4 u[9];
    #pragma unroll
    for (int k = 0; k < 9; ++k) u[k] = *(const uint4*)(pb + k * 8);

    f32x2 fr[36];
    float n1[9];
    #pragma unroll
    for (int k = 0; k < 9; ++k) {
        fr[4 * k + 0] = f32x2{lo16(u[k].x), hi16(u[k].x)};
        fr[4 * k + 1] = f32x2{lo16(u[k].y), hi16(u[k].y)};
        fr[4 * k + 2] = f32x2{lo16(u[k].z), hi16(u[k].z)};
        fr[4 * k + 3] = f32x2{lo16(u[k].w), hi16(u[k].w)};
    }

    // om init = mean over all 72 j: sum over k in-lane, then DPP-sum over i.
    f32x2 om2[4];
    {
        f32x2 s2[4] = {f32x2{0.f, 0.f}, f32x2{0.f, 0.f}, f32x2{0.f, 0.f}, f32x2{0.f, 0.f}};
        #pragma unroll
        for (int k = 0; k < 9; ++k) {
            s2[0] += fr[4 * k + 0];
            s2[1] += fr[4 * k + 1];
            s2[2] += fr[4 * k + 2];
            s2[3] += fr[4 * k + 3];
        }
        #pragma unroll
        for (int q = 0; q < 4; ++q) {
            f32x2 t = red_lo2(s2[q]);
            om2[q] = t * f32x2{1.f / 72.f, 1.f / 72.f};
        }
    }
    float n2 = dot8v(om2[0], om2[1], om2[2], om2[3], om2[0], om2[1], om2[2], om2[3]);

    #pragma unroll
    for (int it = 0; it < 3; ++it) {
        float se = 0.f;
        f32x2 acc2[4] = {f32x2{0.f, 0.f}, f32x2{0.f, 0.f}, f32x2{0.f, 0.f}, f32x2{0.f, 0.f}};
        #pragma unroll
        for (int k = 0; k < 9; ++k) {
            if (it == 0)
                n1[k] = dot8v(fr[4 * k], fr[4 * k + 1], fr[4 * k + 2], fr[4 * k + 3],
                              fr[4 * k], fr[4 * k + 1], fr[4 * k + 2], fr[4 * k + 3]);
            float d = dot8v(fr[4 * k], fr[4 * k + 1], fr[4 * k + 2], fr[4 * k + 3],
                            om2[0], om2[1], om2[2], om2[3]);
            float denom = fmaxf(n1[k] + n2 - d, 1e-8f);
            float e = __expf(d * __builtin_amdgcn_rcpf(denom));
            se += e;
            f32x2 ev{e, e};
            acc2[0] = fma2(ev, fr[4 * k + 0], acc2[0]);
            acc2[1] = fma2(ev, fr[4 * k + 1], acc2[1]);
            acc2[2] = fma2(ev, fr[4 * k + 2], acc2[2]);
            acc2[3] = fma2(ev, fr[4 * k + 3], acc2[3]);
        }
        se = red_lo(se);
        #pragma unroll
        for (int q = 0; q < 4; ++q) acc2[q] = red_lo2(acc2[q]);
        float inv = __builtin_amdgcn_rcpf(se);
        f32x2 iv{inv, inv};
        #pragma unroll
        for (int q = 0; q < 4; ++q) om2[q] = acc2[q] * iv;
        n2 = dot8v(om2[0], om2[1], om2[2], om2[3], om2[0], om2[1], om2[2], om2[3]);
    }

    if (i == 0) {
        const int o = opair * 2 + o2;
        uint4 pk;
        pk.x = pk2bf(om2[0].x, om2[0].y);
        pk.y = pk2bf(om2[1].x, om2[1].y);
        pk.z = pk2bf(om2[2].x, om2[2].y);
        pk.w = pk2bf(om2[3].x, om2[3].y);
        *(uint4*)&yout[((b * 96 + y) * 96 + x0 + pos) * 64 + o * 8] = pk;
        // park f32 finals for BN stats (patch region, dead)
        float4 o0 = {om2[0].x, om2[0].y, om2[1].x, om2[1].y};
        float4 o1 = {om2[2].x, om2[2].y, om2[3].x, om2[3].y};
        *(float4*)&omF[unit * 8] = o0;
        *(float4*)&omF[unit * 8 + 4] = o1;
    }
    __syncthreads();

    // ---- BN stat partials: this block's 16 channels, sum over 16 positions ----
    if (tid < 32) {
        int c16 = tid & 15, sel = tid >> 4;
        int oo2 = c16 >> 3, m = c16 & 7;
        float v = 0.f;
        #pragma unroll
        for (int pp = 0; pp < 16; ++pp) {
            float t = omF[(oo2 * 16 + pp) * 8 + m];
            v += sel ? t * t : t;
        }
        int cp = (blockIdx.x + blockIdx.y * 3 + blockIdx.z) & 7;
        atomicAdd(&statL[cp * 128 + sel * 64 + (opair * 2 + oo2) * 8 + m], v);
    }
}

// ---------------------------------------------------------------------------
// Final: out[b][c][y][x] = x + bn2(y2); bn2 params computed inline per block.
// ---------------------------------------------------------------------------
__launch_bounds__(256)
__global__ void final_kernel(const void* __restrict__ xin,
                             const __hip_bfloat16* __restrict__ yt2,
                             const float* __restrict__ statL,
                             const void* __restrict__ gamma, const void* __restrict__ beta,
                             const void* __restrict__ w1,
                             void* __restrict__ outp) {
    __shared__ float tile[64 * 33];
    __shared__ float scL[64], shL[64];
    const int is32 = detect_is32((const unsigned short*)w1);
    if (threadIdx.x < 64) {
        int c = threadIdx.x;
        float s = 0.f, ss = 0.f;
        #pragma unroll
        for (int cp = 0; cp < 8; ++cp) {
            s  += statL[cp * 128 + c];
            ss += statL[cp * 128 + 64 + c];
        }
        float mean = s * (1.f / (float)NPC);
        float var  = fmaxf(ss * (1.f / (float)NPC) - mean * mean, 0.f);
        float inv  = rsqrtf(var + 1e-5f);
        float g = load_in(gamma, c, is32) * inv;
        scL[c] = g;
        shL[c] = load_in(beta, c, is32) - mean * g;
    }
    __syncthreads();

    int x0 = blockIdx.x * 32, y = blockIdx.y, b = blockIdx.z;
    for (int e = threadIdx.x; e < 1024; e += 256) {
        int c2 = e & 31, xl = e >> 5;
        unsigned v = *(const unsigned*)&yt2[((b * 96 + y) * 96 + x0 + xl) * 64 + c2 * 2];
        int c = c2 * 2;
        tile[c * 33 + xl]       = lo16(v) * scL[c]     + shL[c];
        tile[(c + 1) * 33 + xl] = hi16(v) * scL[c + 1] + shL[c + 1];
    }
    __syncthreads();
    for (int f = threadIdx.x; f < 2048; f += 256) {
        int xl = f & 31, c = f >> 5;
        int idx = ((b * 64 + c) * 96 + y) * 96 + x0 + xl;
        float v = load_in(xin, idx, is32) + tile[c * 33 + xl];
        if (is32) ((float*)outp)[idx] = v;
        else      ((__hip_bfloat16*)outp)[idx] = __float2bfloat16(v);
    }
}

// ---------------------------------------------------------------------------
extern "C" void kernel_launch(void* const* d_in, const int* in_sizes, int n_in,
                              void* d_out, int out_size, void* d_ws, size_t ws_size,
                              hipStream_t stream) {
    const void* x  = d_in[0];
    const void* w1 = d_in[1];
    const void* g1 = d_in[2];
    const void* b1 = d_in[3];
    const void* w2 = d_in[4];
    const void* g2 = d_in[5];
    const void* b2 = d_in[6];

    __hip_bfloat16* bufA = (__hip_bfloat16*)d_ws;   // xt / yt2 (bf16, aliased)
    __hip_bfloat16* bufB = bufA + NELEM;            // yt1 (bf16)
    __hip_bfloat16* Bfr1 = bufB + NELEM;            // 147456 bf16
    __hip_bfloat16* Bfr2 = Bfr1 + 147456;           // 147456 bf16
    float* statz = (float*)(Bfr2 + 147456);         // 2048 f32
    float* statL1 = statz;
    float* statL2 = statz + 1024;

    prep_kernel<<<721, 256, 0, stream>>>(x, w1, w2, bufA, Bfr1, Bfr2, statz);

    dim3 cgrid(24, 96, 2);   // (xtile of 16 x 4 o-pairs), rows, batch
    caps_kernel<<<cgrid, 256, 0, stream>>>(bufA, nullptr, nullptr, nullptr, w1,
                                           Bfr1, bufB, statL1, 1);
    caps_kernel<<<cgrid, 256, 0, stream>>>(bufB, statL1, g1, b1, w1,
                                           Bfr2, bufA, statL2, 0);
    final_kernel<<<dim3(3, 96, 2), 256, 0, stream>>>(x, bufA, statL2, g2, b2, w1, d_out);
}